// Round 3
// baseline (496.136 us; speedup 1.0000x reference)
//
#include <hip/hip_runtime.h>

#define G      1024
#define NNODES 65536
#define NEDGES 262144
#define D      256
#define DIN    768
#define DHID   512
#define DOUT   256
#define CW     512            // collected row width: [edge_agg | node_agg]

#define AGG_BLOCKS 1024       // x 4 waves = 4096 waves
#define EROWS      64         // edge rows per wave  (4096*64 = 262144)
#define NROWS      16         // node rows per wave  (4096*16 = 65536)

__device__ __forceinline__ void flush_acc(float* __restrict__ dst, int cur, int col,
                                          float4& acc) {
    float* p = dst + (size_t)cur * CW + col;
    atomicAdd(p + 0, acc.x); atomicAdd(p + 1, acc.y);
    atomicAdd(p + 2, acc.z); atomicAdd(p + 3, acc.w);
    acc.x = acc.y = acc.z = acc.w = 0.f;
}

__device__ __forceinline__ void row_step(int id, const float4 v, int& cur, float4& acc,
                                         float* __restrict__ dst, int col) {
    if (id != cur) { flush_acc(dst, cur, col, acc); cur = id; }
    acc.x += v.x; acc.y += v.y; acc.z += v.z; acc.w += v.w;
}

// Load one 8-row group: 8 KiB contiguous (rows r..r+7, lane covers 16 B of each
// row) + the 8 ids. All 10 loads are independent — issued as one burst.
__device__ __forceinline__ void load_group(const float4* __restrict__ src,
                                           const int* __restrict__ ids, int r, int lane,
                                           float4 v[8], int4& i0, int4& i1) {
    const float4* p = src + (size_t)r * (D / 4) + lane;
#pragma unroll
    for (int j = 0; j < 8; ++j) v[j] = p[j * (D / 4)];
    i0 = *(const int4*)&ids[r];
    i1 = *(const int4*)&ids[r + 4];
}

__device__ __forceinline__ void proc_group(const float4 v[8], int4 i0, int4 i1,
                                           int& cur, float4& acc,
                                           float* __restrict__ dst, int col) {
    if (i0.x == cur && i1.w == cur) {   // whole group inside current run (common)
        acc.x += ((v[0].x + v[1].x) + (v[2].x + v[3].x)) + ((v[4].x + v[5].x) + (v[6].x + v[7].x));
        acc.y += ((v[0].y + v[1].y) + (v[2].y + v[3].y)) + ((v[4].y + v[5].y) + (v[6].y + v[7].y));
        acc.z += ((v[0].z + v[1].z) + (v[2].z + v[3].z)) + ((v[4].z + v[5].z) + (v[6].z + v[7].z));
        acc.w += ((v[0].w + v[1].w) + (v[2].w + v[3].w)) + ((v[4].w + v[5].w) + (v[6].w + v[7].w));
    } else {                            // run boundary inside the group
        row_step(i0.x, v[0], cur, acc, dst, col);
        row_step(i0.y, v[1], cur, acc, dst, col);
        row_step(i0.z, v[2], cur, acc, dst, col);
        row_step(i0.w, v[3], cur, acc, dst, col);
        row_step(i1.x, v[4], cur, acc, dst, col);
        row_step(i1.y, v[5], cur, acc, dst, col);
        row_step(i1.z, v[6], cur, acc, dst, col);
        row_step(i1.w, v[7], cur, acc, dst, col);
    }
}

// Sorted-segment sum with register ping-pong pipeline: group k+1's loads are
// issued before group k's accumulate, so ~8-16 KiB stays in flight per wave at
// all times (no vmcnt(0) drain in steady state). Flush via atomicAdd only at
// run boundaries (~1.25 per wave on average).
__device__ __forceinline__ void seg_sum_pipelined(
        const float4* __restrict__ src, const int* __restrict__ ids,
        float* __restrict__ dst, int col, int r, int ngroups, int lane) {
    float4 va[8], vb[8];
    int4 ia0, ia1, ib0, ib1;
    float4 acc = {0.f, 0.f, 0.f, 0.f};
    int cur = ids[r];

    load_group(src, ids, r, lane, va, ia0, ia1);
    for (int gpair = 0; gpair < ngroups / 2 - 1; ++gpair) {
        load_group(src, ids, r + 8, lane, vb, ib0, ib1);
        proc_group(va, ia0, ia1, cur, acc, dst, col);
        r += 8;
        load_group(src, ids, r + 8, lane, va, ia0, ia1);
        proc_group(vb, ib0, ib1, cur, acc, dst, col);
        r += 8;
    }
    load_group(src, ids, r + 8, lane, vb, ib0, ib1);
    proc_group(va, ia0, ia1, cur, acc, dst, col);
    proc_group(vb, ib0, ib1, cur, acc, dst, col);
    flush_acc(dst, cur, col, acc);
}

// 1024 blocks x 256 thr, launch_bounds(256,4) -> 16 waves/CU, no LDS.
// Wave W: edge rows [W*64, +64) then node rows [W*16, +16), contiguous.
// BW-bound by model (~320 MB @ ~6.3 TB/s ≈ 51 µs floor) — unchanged (control).
__global__ __launch_bounds__(256, 4) void fused_agg(
        const float4* __restrict__ nodes,
        const float4* __restrict__ edges,
        const int* __restrict__ nids,
        const int* __restrict__ eids,
        float* __restrict__ collected) {
    const int lane = threadIdx.x & 63;
    const int wave = threadIdx.x >> 6;
    const int W    = blockIdx.x * 4 + wave;         // 0..4095

    seg_sum_pipelined(edges, eids, collected, lane * 4,       W * EROWS, EROWS / 8, lane);
    seg_sum_pipelined(nodes, nids, collected, D + lane * 4,   W * NROWS, NROWS / 8, lane);
}

// Fused 2-layer MLP with split-K stage 2.
// Grid: (8 h-col blocks) x (32 row tiles) = 256 blocks (full CU coverage,
// the property r2's regression proved essential), 256 thr.
// Stage 1 == r0's known-good GEMM1 block: Htile[32 rows][64 h-cols] =
//   relu(collected_row @ W1[:, hc*64..+64] + b1), K=768 (split A: collected
//   cols [0,512) + globals_ cols [512,768)), reg->LDS double buffer, micro 2x4.
// Stage 2: Htile (LDS) @ W2[hc*64..+64, 0:256] -> 32x256 partial, atomicAdd
//   into out (zero-init'd). Kills GEMM2's 128-block launch + the h round-trip.
__global__ __launch_bounds__(256) void mlp_fused(
        const float* __restrict__ A1, const float* __restrict__ A2,
        const float* __restrict__ W1, const float* __restrict__ b1,
        const float* __restrict__ W2, const float* __restrict__ b2,
        float* __restrict__ out) {
    __shared__ float At[2][32][34];
    __shared__ __align__(16) float Bs[2][32][64];
    __shared__ __align__(16) float Hs[32][64];

    const int tid = threadIdx.x;
    const int tx = tid & 15;          // h-col group (float4)
    const int ty = tid >> 4;          // row pair
    const int hc = blockIdx.x;        // h-col block 0..7
    const int m0 = blockIdx.y * 32;
    const int n0 = hc * 64;

    const int ar = tid >> 3;          // A-tile row 0..31
    const int ac = (tid & 7) * 4;     // A-tile k-offset (float4)
    const int br = tid >> 3;          // B-tile k-row 0..31
    const int bc = (tid & 7) * 8;     // B-tile col (2x float4)

    const int arow = m0 + ar;
    const float* Bptr = W1 + (size_t)br * DHID + n0 + bc;

    auto loadA = [&](int kc) -> float4 {
        return (kc < CW) ? *(const float4*)&A1[(size_t)arow * CW + kc + ac]
                         : *(const float4*)&A2[(size_t)arow * D + (kc - CW) + ac];
    };

    {
        const float4 a4  = loadA(0);
        const float4 b40 = *(const float4*)Bptr;
        const float4 b41 = *(const float4*)(Bptr + 4);
        At[0][ac + 0][ar] = a4.x; At[0][ac + 1][ar] = a4.y;
        At[0][ac + 2][ar] = a4.z; At[0][ac + 3][ar] = a4.w;
        *(float4*)&Bs[0][br][bc]     = b40;
        *(float4*)&Bs[0][br][bc + 4] = b41;
    }
    __syncthreads();

    float4 acc0 = {0.f, 0.f, 0.f, 0.f};
    float4 acc1 = {0.f, 0.f, 0.f, 0.f};
    int buf = 0;

    for (int kt = 0; kt < DIN; kt += 32) {
        const bool has_next = (kt + 32) < DIN;
        float4 na, nb0, nb1;
        if (has_next) {
            na  = loadA(kt + 32);
            nb0 = *(const float4*)(Bptr + (size_t)(kt + 32) * DHID);
            nb1 = *(const float4*)(Bptr + (size_t)(kt + 32) * DHID + 4);
        }
#pragma unroll
        for (int k = 0; k < 32; ++k) {
            const float2 a2 = *(const float2*)&At[buf][k][ty * 2];
            const float4 bv = *(const float4*)&Bs[buf][k][tx * 4];
            acc0.x += a2.x * bv.x; acc0.y += a2.x * bv.y;
            acc0.z += a2.x * bv.z; acc0.w += a2.x * bv.w;
            acc1.x += a2.y * bv.x; acc1.y += a2.y * bv.y;
            acc1.z += a2.y * bv.z; acc1.w += a2.y * bv.w;
        }
        if (has_next) {
            const int nb = buf ^ 1;
            At[nb][ac + 0][ar] = na.x; At[nb][ac + 1][ar] = na.y;
            At[nb][ac + 2][ar] = na.z; At[nb][ac + 3][ar] = na.w;
            *(float4*)&Bs[nb][br][bc]     = nb0;
            *(float4*)&Bs[nb][br][bc + 4] = nb1;
            __syncthreads();
            buf = nb;
        }
    }

    // bias + relu -> Hs
    {
        const float4 bv = *(const float4*)&b1[n0 + tx * 4];
        float4 o0, o1;
        o0.x = fmaxf(acc0.x + bv.x, 0.f); o0.y = fmaxf(acc0.y + bv.y, 0.f);
        o0.z = fmaxf(acc0.z + bv.z, 0.f); o0.w = fmaxf(acc0.w + bv.w, 0.f);
        o1.x = fmaxf(acc1.x + bv.x, 0.f); o1.y = fmaxf(acc1.y + bv.y, 0.f);
        o1.z = fmaxf(acc1.z + bv.z, 0.f); o1.w = fmaxf(acc1.w + bv.w, 0.f);
        *(float4*)&Hs[ty * 2][tx * 4]     = o0;
        *(float4*)&Hs[ty * 2 + 1][tx * 4] = o1;
    }
    __syncthreads();

    // Stage 2: Hs[32][64] @ W2[hc*64..+64][0:256] -> partial out[32][256].
    // Thread: rows rg*8..+8, cols c2..c2+3 (wave-uniform rg -> Hs reads are
    // broadcast, no bank conflict; W2 float4 loads coalesced, L2-resident).
    const int c2 = (tid & 63) * 4;
    const int rg = tid >> 6;
    float acc2[8][4] = {};
    const float* W2p = W2 + (size_t)n0 * DOUT + c2;
#pragma unroll 4
    for (int k0 = 0; k0 < 64; k0 += 4) {
        float4 w[4];
#pragma unroll
        for (int j = 0; j < 4; ++j)
            w[j] = *(const float4*)(W2p + (size_t)(k0 + j) * DOUT);
#pragma unroll
        for (int r = 0; r < 8; ++r) {
            const float4 h4 = *(const float4*)&Hs[rg * 8 + r][k0];
            acc2[r][0] += h4.x * w[0].x + h4.y * w[1].x + h4.z * w[2].x + h4.w * w[3].x;
            acc2[r][1] += h4.x * w[0].y + h4.y * w[1].y + h4.z * w[2].y + h4.w * w[3].y;
            acc2[r][2] += h4.x * w[0].z + h4.y * w[1].z + h4.z * w[2].z + h4.w * w[3].z;
            acc2[r][3] += h4.x * w[0].w + h4.y * w[1].w + h4.z * w[2].w + h4.w * w[3].w;
        }
    }
    if (hc == 0) {                       // add b2 exactly once
        const float4 b = *(const float4*)&b2[c2];
#pragma unroll
        for (int r = 0; r < 8; ++r) {
            acc2[r][0] += b.x; acc2[r][1] += b.y;
            acc2[r][2] += b.z; acc2[r][3] += b.w;
        }
    }
#pragma unroll
    for (int r = 0; r < 8; ++r) {
        float* p = out + (size_t)(m0 + rg * 8 + r) * DOUT + c2;
        atomicAdd(p + 0, acc2[r][0]); atomicAdd(p + 1, acc2[r][1]);
        atomicAdd(p + 2, acc2[r][2]); atomicAdd(p + 3, acc2[r][3]);
    }
}

extern "C" void kernel_launch(void* const* d_in, const int* in_sizes, int n_in,
                              void* d_out, int out_size, void* d_ws, size_t ws_size,
                              hipStream_t stream) {
    const float* nodes    = (const float*)d_in[0];
    const float* edges    = (const float*)d_in[1];
    const float* globals_ = (const float*)d_in[2];
    const int*   nids     = (const int*)d_in[3];
    const int*   eids     = (const int*)d_in[4];
    const float* W1       = (const float*)d_in[5];
    const float* b1       = (const float*)d_in[6];
    const float* W2       = (const float*)d_in[7];
    const float* b2       = (const float*)d_in[8];
    float* out = (float*)d_out;

    float* collected = (float*)d_ws;                 // [G, 512] (2 MB), atomic-accumulated

    // zero accumulators: collected (ws re-poisoned 0xAA) and out (split-K atomics)
    hipMemsetAsync(collected, 0, (size_t)G * CW * sizeof(float), stream);
    hipMemsetAsync(out, 0, (size_t)G * DOUT * sizeof(float), stream);

    fused_agg<<<AGG_BLOCKS, 256, 0, stream>>>(
        (const float4*)nodes, (const float4*)edges, nids, eids, collected);

    // Fused MLP: grid 8 x 32 = 256 blocks, full CU coverage
    mlp_fused<<<dim3(DHID / 64, G / 32), 256, 0, stream>>>(
        collected, globals_, W1, b1, W2, b2, out);
}

// Round 4
// 455.339 us; speedup vs baseline: 1.0896x; 1.0896x over previous
//
#include <hip/hip_runtime.h>

#define G      1024
#define NNODES 65536
#define NEDGES 262144
#define D      256
#define DIN    768
#define DHID   512
#define DOUT   256
#define CW     512            // collected row width: [edge_agg | node_agg]

// ---------------------------------------------------------------------------
// Aggregation, atomic-free: one block per graph. Sorted ids -> each graph is a
// contiguous row range; block finds its bounds by binary search (4 lanes in
// parallel, ~18 dependent L2 loads ~2us, all 1024 blocks concurrent), streams
// the rows (float4/lane = one full 1KB row per wave-instruction, 4-row bursts
// = 4KB in flight/wave; 16 waves/CU >> the 9.2KB/CU needed for 6.3TB/s),
// LDS-reduces across the 4 waves, writes each collected row EXACTLY once.
// Removes r0's memset node + ~3.7M device-scope atomic RMWs (r3 measured
// ~6.5ns marginal per lane-atomic -> ~15-25us saved).
// ---------------------------------------------------------------------------

__device__ __forceinline__ int lb_sorted(const int* __restrict__ a, int n, int v) {
    int lo = 0, hi = n;
    while (lo < hi) { int m = (lo + hi) >> 1; if (a[m] < v) lo = m + 1; else hi = m; }
    return lo;
}

// Sum rows [s,e) of src (rows of D=256 floats); this lane owns cols lane*4..+3.
// Wave w takes 4-row groups w, w+4, w+8, ... (4 independent loads per group);
// tail rows (<4) handled by wave 0.
__device__ __forceinline__ float4 seg_sum_rows(const float4* __restrict__ src,
                                               int s, int e, int w, int lane) {
    float4 acc = {0.f, 0.f, 0.f, 0.f};
    const int n = e - s;
    const int ngrp = n >> 2;
    for (int gi = w; gi < ngrp; gi += 4) {
        const float4* p = src + (size_t)(s + gi * 4) * (D / 4) + lane;
        const float4 v0 = p[0];
        const float4 v1 = p[D / 4];
        const float4 v2 = p[2 * (D / 4)];
        const float4 v3 = p[3 * (D / 4)];
        acc.x += (v0.x + v1.x) + (v2.x + v3.x);
        acc.y += (v0.y + v1.y) + (v2.y + v3.y);
        acc.z += (v0.z + v1.z) + (v2.z + v3.z);
        acc.w += (v0.w + v1.w) + (v2.w + v3.w);
    }
    if (w == 0) {
        for (int r = s + (ngrp << 2); r < e; ++r) {
            const float4 v = src[(size_t)r * (D / 4) + lane];
            acc.x += v.x; acc.y += v.y; acc.z += v.z; acc.w += v.w;
        }
    }
    return acc;
}

__global__ __launch_bounds__(256, 4) void agg_per_graph(
        const float4* __restrict__ nodes,
        const float4* __restrict__ edges,
        const int* __restrict__ nids,
        const int* __restrict__ eids,
        float* __restrict__ collected) {
    __shared__ int seg[4];
    __shared__ float ered[4][256];
    __shared__ float nred[4][256];

    const int tid  = threadIdx.x;
    const int lane = tid & 63;
    const int w    = tid >> 6;
    const int g    = blockIdx.x;

    if (tid < 4) {                       // 4 searches in one wave, lock-step
        const int* a = (tid < 2) ? eids : nids;
        const int  n = (tid < 2) ? NEDGES : NNODES;
        seg[tid] = lb_sorted(a, n, g + (tid & 1));
    }
    __syncthreads();
    const int es = seg[0], ee = seg[1], ns = seg[2], ne = seg[3];

    const float4 ea = seg_sum_rows(edges, es, ee, w, lane);
    const float4 na = seg_sum_rows(nodes, ns, ne, w, lane);

    *(float4*)&ered[w][lane * 4] = ea;
    *(float4*)&nred[w][lane * 4] = na;
    __syncthreads();

    const float ev = (ered[0][tid] + ered[1][tid]) + (ered[2][tid] + ered[3][tid]);
    const float nv = (nred[0][tid] + nred[1][tid]) + (nred[2][tid] + nred[3][tid]);
    collected[(size_t)g * CW + tid]       = ev;
    collected[(size_t)g * CW + 256 + tid] = nv;
}

// ---------------------------------------------------------------------------
// GEMM1 — byte-identical to r0's known-good kernel (456us config): tile 32x64,
// TK=32, 256 thr, micro 2x4, k-major A in LDS (+2 pad), reg->LDS double
// buffer. A split: cols [0,asplit) from A1 (stride s1), [asplit,K) from A2.
// ---------------------------------------------------------------------------
__global__ __launch_bounds__(256) void gemm_bias_act(
        const float* __restrict__ A1, const float* __restrict__ A2,
        const float* __restrict__ B,
        const float* __restrict__ bias, float* __restrict__ C,
        int N, int K, int asplit, int s1, int s2, int relu) {
    __shared__ float At[2][32][34];
    __shared__ __align__(16) float Bs[2][32][64];

    const int tid = threadIdx.x;
    const int tx = tid & 15;
    const int ty = tid >> 4;
    const int m0 = blockIdx.y * 32;
    const int n0 = blockIdx.x * 64;

    const int ar = tid >> 3;
    const int ac = (tid & 7) * 4;
    const int br = tid >> 3;
    const int bc = (tid & 7) * 8;

    const int arow = m0 + ar;
    const float* Bptr = B + (size_t)br * N + n0 + bc;

    auto loadA = [&](int kc) -> float4 {
        return (kc < asplit) ? *(const float4*)&A1[(size_t)arow * s1 + kc + ac]
                             : *(const float4*)&A2[(size_t)arow * s2 + (kc - asplit) + ac];
    };

    {
        const float4 a4  = loadA(0);
        const float4 b40 = *(const float4*)Bptr;
        const float4 b41 = *(const float4*)(Bptr + 4);
        At[0][ac + 0][ar] = a4.x; At[0][ac + 1][ar] = a4.y;
        At[0][ac + 2][ar] = a4.z; At[0][ac + 3][ar] = a4.w;
        *(float4*)&Bs[0][br][bc]     = b40;
        *(float4*)&Bs[0][br][bc + 4] = b41;
    }
    __syncthreads();

    float4 acc0 = {0.f, 0.f, 0.f, 0.f};
    float4 acc1 = {0.f, 0.f, 0.f, 0.f};
    int buf = 0;

    for (int kt = 0; kt < K; kt += 32) {
        const bool has_next = (kt + 32) < K;
        float4 na, nb0, nb1;
        if (has_next) {
            na  = loadA(kt + 32);
            nb0 = *(const float4*)(Bptr + (size_t)(kt + 32) * N);
            nb1 = *(const float4*)(Bptr + (size_t)(kt + 32) * N + 4);
        }
#pragma unroll
        for (int k = 0; k < 32; ++k) {
            const float2 a2 = *(const float2*)&At[buf][k][ty * 2];
            const float4 bv = *(const float4*)&Bs[buf][k][tx * 4];
            acc0.x += a2.x * bv.x; acc0.y += a2.x * bv.y;
            acc0.z += a2.x * bv.z; acc0.w += a2.x * bv.w;
            acc1.x += a2.y * bv.x; acc1.y += a2.y * bv.y;
            acc1.z += a2.y * bv.z; acc1.w += a2.y * bv.w;
        }
        if (has_next) {
            const int nb = buf ^ 1;
            At[nb][ac + 0][ar] = na.x; At[nb][ac + 1][ar] = na.y;
            At[nb][ac + 2][ar] = na.z; At[nb][ac + 3][ar] = na.w;
            *(float4*)&Bs[nb][br][bc]     = nb0;
            *(float4*)&Bs[nb][br][bc + 4] = nb1;
            __syncthreads();
            buf = nb;
        }
    }

    const int col = n0 + tx * 4;
    const int row = m0 + ty * 2;
    const float4 bv = *(const float4*)&bias[col];
    float4 o0, o1;
    o0.x = acc0.x + bv.x; o0.y = acc0.y + bv.y; o0.z = acc0.z + bv.z; o0.w = acc0.w + bv.w;
    o1.x = acc1.x + bv.x; o1.y = acc1.y + bv.y; o1.z = acc1.z + bv.z; o1.w = acc1.w + bv.w;
    if (relu) {
        o0.x = fmaxf(o0.x, 0.f); o0.y = fmaxf(o0.y, 0.f);
        o0.z = fmaxf(o0.z, 0.f); o0.w = fmaxf(o0.w, 0.f);
        o1.x = fmaxf(o1.x, 0.f); o1.y = fmaxf(o1.y, 0.f);
        o1.z = fmaxf(o1.z, 0.f); o1.w = fmaxf(o1.w, 0.f);
    }
    *(float4*)&C[(size_t)row * N + col] = o0;
    *(float4*)&C[(size_t)(row + 1) * N + col] = o1;
}

// ---------------------------------------------------------------------------
// GEMM2 at full CU coverage: C[1024,256] = h[1024,512] @ W2 + b2. Tile 16x64
// -> grid (4,64) = 256 blocks (r2 proved coverage >> per-wave efficiency;
// r0's 32x64 tiling gave only 128 blocks = half the GPU idle). 256 thr,
// micro 1x4, same reg->LDS double-buffer schedule as GEMM1.
// ---------------------------------------------------------------------------
__global__ __launch_bounds__(256) void gemm2_bias(
        const float* __restrict__ A, const float* __restrict__ B,
        const float* __restrict__ bias, float* __restrict__ C) {
    __shared__ float At[2][32][17];                  // k-major [k][m], m=0..15
    __shared__ __align__(16) float Bs[2][32][64];

    const int tid = threadIdx.x;
    const int tx = tid & 15;          // output col group (float4)
    const int ty = tid >> 4;          // output row 0..15
    const int m0 = blockIdx.y * 16;
    const int n0 = blockIdx.x * 64;

    const int ar = (tid >> 3) & 15;   // A-tile row (tid<128 active)
    const int ac = (tid & 7) * 4;     // A-tile k-offset (float4)
    const int br = tid >> 3;          // B-tile k-row 0..31
    const int bc = (tid & 7) * 8;     // B-tile col (2x float4)

    const float* Aptr = A + (size_t)(m0 + ar) * DHID + ac;
    const float* Bptr = B + (size_t)br * DOUT + n0 + bc;

    {
        const float4 b40 = *(const float4*)Bptr;
        const float4 b41 = *(const float4*)(Bptr + 4);
        *(float4*)&Bs[0][br][bc]     = b40;
        *(float4*)&Bs[0][br][bc + 4] = b41;
        if (tid < 128) {
            const float4 a4 = *(const float4*)Aptr;
            At[0][ac + 0][ar] = a4.x; At[0][ac + 1][ar] = a4.y;
            At[0][ac + 2][ar] = a4.z; At[0][ac + 3][ar] = a4.w;
        }
    }
    __syncthreads();

    float4 acc = {0.f, 0.f, 0.f, 0.f};
    int buf = 0;

    for (int kt = 0; kt < DHID; kt += 32) {
        const bool has_next = (kt + 32) < DHID;
        float4 na, nb0, nb1;
        if (has_next) {
            nb0 = *(const float4*)(Bptr + (size_t)(kt + 32) * DOUT);
            nb1 = *(const float4*)(Bptr + (size_t)(kt + 32) * DOUT + 4);
            if (tid < 128) na = *(const float4*)(Aptr + (kt + 32));
        }
#pragma unroll
        for (int k = 0; k < 32; ++k) {
            const float a   = At[buf][k][ty];              // 16-addr broadcast
            const float4 bv = *(const float4*)&Bs[buf][k][tx * 4];
            acc.x += a * bv.x; acc.y += a * bv.y;
            acc.z += a * bv.z; acc.w += a * bv.w;
        }
        if (has_next) {
            const int nb = buf ^ 1;
            *(float4*)&Bs[nb][br][bc]     = nb0;
            *(float4*)&Bs[nb][br][bc + 4] = nb1;
            if (tid < 128) {
                At[nb][ac + 0][ar] = na.x; At[nb][ac + 1][ar] = na.y;
                At[nb][ac + 2][ar] = na.z; At[nb][ac + 3][ar] = na.w;
            }
            __syncthreads();
            buf = nb;
        }
    }

    const int col = n0 + tx * 4;
    const float4 bv = *(const float4*)&bias[col];
    float4 o;
    o.x = acc.x + bv.x; o.y = acc.y + bv.y;
    o.z = acc.z + bv.z; o.w = acc.w + bv.w;
    *(float4*)&C[(size_t)(m0 + ty) * DOUT + col] = o;
}

extern "C" void kernel_launch(void* const* d_in, const int* in_sizes, int n_in,
                              void* d_out, int out_size, void* d_ws, size_t ws_size,
                              hipStream_t stream) {
    const float* nodes    = (const float*)d_in[0];
    const float* edges    = (const float*)d_in[1];
    const float* globals_ = (const float*)d_in[2];
    const int*   nids     = (const int*)d_in[3];
    const int*   eids     = (const int*)d_in[4];
    const float* W1       = (const float*)d_in[5];
    const float* b1       = (const float*)d_in[6];
    const float* W2       = (const float*)d_in[7];
    const float* b2       = (const float*)d_in[8];
    float* out = (float*)d_out;

    float* collected = (float*)d_ws;                 // [G, 512] (2 MB), written exactly once
    float* h         = collected + (size_t)G * CW;   // [G, DHID] (2 MB), fully written

    // No memsets: collected fully written by agg_per_graph, h by GEMM1.

    agg_per_graph<<<G, 256, 0, stream>>>(
        (const float4*)nodes, (const float4*)edges, nids, eids, collected);

    // GEMM1: A = [collected | globals_] (K=768 split at 512), relu. grid 8x32 = 256 blocks
    gemm_bias_act<<<dim3(DHID / 64, G / 32), 256, 0, stream>>>(
        collected, globals_, W1, b1, h, DHID, DIN, CW, CW, D, 1);

    // GEMM2: 16x64 tiles -> grid 4x64 = 256 blocks (full coverage)
    gemm2_bias<<<dim3(DOUT / 64, G / 16), 256, 0, stream>>>(h, W2, b2, out);
}